// Round 10
// baseline (52.540 us; speedup 1.0000x reference)
//
#include <hip/hip_runtime.h>

typedef float    f32x4 __attribute__((ext_vector_type(4)));
typedef _Float16 half8 __attribute__((ext_vector_type(8)));

#define PLN   256
#define FY    66
#define FX    68
#define FSITE (FY * FX)   // 4488 sites per plane

// ---------------- k1: dense feature map (padded, per input pixel) ----------
// site (pl, y, xx) <-> input pixel (y-1, xx-1) of plane pl (v=0 outside).
// Writes: fs[site] = 8 f16 spline basis values; fb[site] = f32 silu.
__global__ __launch_bounds__(256) void kan_feat_kernel(
    const float* __restrict__ x, half8* __restrict__ fs, float* __restrict__ fb)
{
    const int idx = blockIdx.x * 256 + threadIdx.x;
    if (idx >= PLN * FSITE) return;
    const int pl = idx / FSITE;
    const int rm = idx - pl * FSITE;
    const int y  = rm / FX;
    const int xx = rm - y * FX;
    const int gy = y - 1, gx = xx - 1;
    const bool inb = ((unsigned)gy < 64u) & ((unsigned)gx < 64u);
    const float v = inb ? x[pl * 4096 + gy * 64 + gx] : 0.f;

    const float s = __fdividef(v, 1.f + __expf(-v));   // silu

    float u  = (v + 2.2f) * 2.5f;
    float mf = floorf(u);
    float t  = u - mf;
    int   m  = (int)mf;
    const bool inr = (m >= 0) && (m <= 10);
    float t2 = t * t, t3 = t2 * t, omt = 1.f - t;
    const float c6 = 1.f / 6.f;
    float wr0 = c6 * omt * omt * omt;
    float wr1 = c6 * (3.f * t3 - 6.f * t2 + 4.f);
    float wr2 = c6 * (-3.f * t3 + 3.f * t2 + 3.f * t + 1.f);
    float wr3 = c6 * t3;
    if (!inr) { wr0 = 0.f; wr1 = 0.f; wr2 = 0.f; wr3 = 0.f; }

    const int base = m - 3;
    half8 hv = {};
    #pragma unroll
    for (int g = 0; g < 8; ++g) {
        const int r = g - base;
        float val = 0.f;
        val = (r == 0) ? wr0 : val;
        val = (r == 1) ? wr1 : val;
        val = (r == 2) ? wr2 : val;
        val = (r == 3) ? wr3 : val;
        hv[g] = (_Float16)val;
    }
    fs[idx] = hv;
    fb[idx] = s;
}

// ---------------- k2: MFMA GEMM from the feature map ----------------------
// Block = 8-row strip x 64 cols of one plane; 4 waves; no LDS, no barrier.
// C[n][p] = sum_k A[n][k] B[k][p], k = tap*8+g (72 used, pad 96).
// Lane (p = lane&15, cc = lane>>4): A row n=p, k-chunk cc; B col p, k-chunk cc.
// B-fragment = one 16B global load of the lane's tap-shifted pixel features.
__global__ __launch_bounds__(256, 4) void kan_gemm_kernel(
    const half8* __restrict__ fs, const float* __restrict__ fb,
    const float* __restrict__ bw, const float* __restrict__ sw,
    const float* __restrict__ ss, float* __restrict__ out)
{
    const int tid  = threadIdx.x;
    const int lane = tid & 63;
    const int wv   = tid >> 6;
    const int p    = lane & 15;
    const int cc   = lane >> 4;
    const int pl   = blockIdx.x >> 3;
    const int r0   = (blockIdx.x & 7) * 8;

    // A-fragments (scaled spline weights), zero-padded beyond tap 8 / n 7
    const int n  = p;
    const int nc = (n < 8) ? n : 0;
    half8 Af[3];
    #pragma unroll
    for (int s = 0; s < 3; ++s) {
        const int tap = (s < 2) ? (s * 4 + cc) : 8;
        const bool ok = (n < 8) && (s < 2 || cc == 0);
        half8 a = {};
        #pragma unroll
        for (int g = 0; g < 8; ++g)
            a[g] = ok ? (_Float16)(sw[(nc * 9 + tap) * 8 + g] * ss[nc * 9 + tap]) : (_Float16)0.f;
        Af[s] = a;
    }
    // base weights rows nb..nb+3 (cc<2 real)
    const int nb = (cc < 2) ? cc * 4 : 0;
    float bwr[4][9];
    #pragma unroll
    for (int r = 0; r < 4; ++r)
        #pragma unroll
        for (int t = 0; t < 9; ++t)
            bwr[r][t] = bw[(nb + r) * 9 + t];

    const half8* __restrict__ fsp = fs + (size_t)pl * FSITE;
    const float* __restrict__ fbp = fb + (size_t)pl * FSITE;
    float* __restrict__ obase = out + (size_t)pl * (8 * 4096);
    const half8 zf = {};

    for (int tau = wv; tau < 32; tau += 4) {
        const int orow = tau >> 2;        // 0..7
        const int colb = tau & 3;
        const int oy   = r0 + orow;
        const int px   = colb * 16 + p;

        half8 Bf[3];
        #pragma unroll
        for (int s = 0; s < 3; ++s) {
            const int tap = (s < 2) ? (s * 4 + cc) : 8;
            const bool ok = (s < 2) || (cc == 0);
            const int di = tap / 3, dj = tap % 3;
            const half8 ld = fsp[(oy + di) * FX + px + dj];
            Bf[s] = ok ? ld : zf;
        }

        f32x4 acc = {0.f, 0.f, 0.f, 0.f};
        acc = __builtin_amdgcn_mfma_f32_16x16x32_f16(Af[0], Bf[0], acc, 0, 0, 0);
        acc = __builtin_amdgcn_mfma_f32_16x16x32_f16(Af[1], Bf[1], acc, 0, 0, 0);
        acc = __builtin_amdgcn_mfma_f32_16x16x32_f16(Af[2], Bf[2], acc, 0, 0, 0);

        float bacc[4] = {0.f, 0.f, 0.f, 0.f};
        #pragma unroll
        for (int di = 0; di < 3; ++di)
            #pragma unroll
            for (int dj = 0; dj < 3; ++dj) {
                const float sv = fbp[(oy + di) * FX + px + dj];
                const int t = di * 3 + dj;
                #pragma unroll
                for (int r = 0; r < 4; ++r)
                    bacc[r] += sv * bwr[r][t];
            }

        if (cc < 2) {
            float* o = obase + (size_t)oy * 64 + px;
            #pragma unroll
            for (int r = 0; r < 4; ++r)
                o[(cc * 4 + r) * 4096] = acc[r] + bacc[r];
        }
    }
}

extern "C" void kernel_launch(void* const* d_in, const int* in_sizes, int n_in,
                              void* d_out, int out_size, void* d_ws, size_t ws_size,
                              hipStream_t stream) {
    const float* x  = (const float*)d_in[0];
    const float* bw = (const float*)d_in[1];
    const float* sw = (const float*)d_in[2];
    const float* ss = (const float*)d_in[3];
    float* out = (float*)d_out;

    half8* fs = (half8*)d_ws;                                  // 18,382,848 B
    float* fb = (float*)((char*)d_ws + (size_t)PLN * FSITE * 16);  // +4,595,712 B

    {
        const int total = PLN * FSITE;
        dim3 block(256, 1, 1);
        dim3 grid((total + 255) / 256, 1, 1);
        hipLaunchKernelGGL(kan_feat_kernel, grid, block, 0, stream, x, fs, fb);
    }
    {
        dim3 block(256, 1, 1);
        dim3 grid(2048, 1, 1);   // 256 planes x 8 strips (8 rows each)
        hipLaunchKernelGGL(kan_gemm_kernel, grid, block, 0, stream,
                           fs, fb, bw, sw, ss, out);
    }
}

// Round 11
// 21.500 us; speedup vs baseline: 2.4437x; 2.4437x over previous
//
#include <hip/hip_runtime.h>

typedef float    f32x4 __attribute__((ext_vector_type(4)));
typedef _Float16 h8    __attribute__((ext_vector_type(8)));
typedef unsigned u32x4 __attribute__((ext_vector_type(4)));

#define STRIP 16
#define SR 18          // site rows (strip + halo)
#define SC 66          // site cols used
#define SCP 68         // padded site col stride

__device__ __forceinline__ unsigned pkf16(float a, float b) {
    return __builtin_bit_cast(unsigned, __builtin_amdgcn_cvt_pkrtz(a, b));
}

// Block = 16-row strip of one (b,c) plane; 4 waves.
// P1: stage per-site basis recs (8 f16, 16B) + silu (f32).
// P2: per-pixel im2col silu vecs: IC0 = f16 silu taps0..7 (16B), IC1 = (silu8,0).
// P3: MFMA 16x16x32_f16, K = 96: chunks 0-8 = spline taps (A = scaled sw,
//     B = site basis vec), chunk 9 = base taps0-7 (A = bw, B = IC0),
//     chunk 10 = base tap8 (A = (bw8,0..), B = IC1), chunk 11 = zero.
//     C row = conv n (lane>>4)*4+reg, col = pixel (lane&15)  [HW-verified R9].
__global__ __launch_bounds__(256, 3) void kan_conv_kernel(
    const float* __restrict__ x,     // (256, 64, 64)
    const float* __restrict__ bw,    // (8, 9)
    const float* __restrict__ sw,    // (8, 9, 8)
    const float* __restrict__ ss,    // (8, 9)
    float* __restrict__ out)         // (256, 8, 64, 64)
{
    __shared__ __align__(16) unsigned BSb[SR * SCP * 4];      // 19584 B
    __shared__ float Sil[SR * SCP];                           //  4896 B
    __shared__ __align__(16) unsigned IC0[STRIP * 64 * 4];    // 16384 B
    __shared__ unsigned IC1[STRIP * 64];                      //  4096 B
    __shared__ __align__(16) unsigned ZR[4];                  //    16 B

    const int tid  = threadIdx.x;
    const int lane = tid & 63;
    const int wv   = tid >> 6;
    const int p    = lane & 15;
    const int cc   = lane >> 4;
    const int pl   = blockIdx.x >> 2;
    const int r0   = (blockIdx.x & 3) * STRIP;

    const float* __restrict__ xin = x + (size_t)pl * 4096;

    if (tid == 0) { ZR[0] = 0; ZR[1] = 0; ZR[2] = 0; ZR[3] = 0; }

    // ---- per-lane A-fragments (once) ----
    const int nc = (p < 8) ? p : (p - 8);   // rows 8..15 duplicate row data; C rows unused
    u32x4 Au[3];
    {
        auto packw = [&](int tap) -> u32x4 {
            const float scs = ss[nc * 9 + tap];
            float w[8];
            #pragma unroll
            for (int g = 0; g < 8; ++g) w[g] = sw[(nc * 9 + tap) * 8 + g] * scs;
            u32x4 r;
            r[0] = pkf16(w[0], w[1]); r[1] = pkf16(w[2], w[3]);
            r[2] = pkf16(w[4], w[5]); r[3] = pkf16(w[6], w[7]);
            return r;
        };
        Au[0] = packw(cc);
        Au[1] = packw(4 + cc);
        u32x4 a2 = {0u, 0u, 0u, 0u};
        if (cc == 0) a2 = packw(8);
        else if (cc == 1) {
            a2[0] = pkf16(bw[nc * 9 + 0], bw[nc * 9 + 1]);
            a2[1] = pkf16(bw[nc * 9 + 2], bw[nc * 9 + 3]);
            a2[2] = pkf16(bw[nc * 9 + 4], bw[nc * 9 + 5]);
            a2[3] = pkf16(bw[nc * 9 + 6], bw[nc * 9 + 7]);
        } else if (cc == 2) {
            a2[0] = pkf16(bw[nc * 9 + 8], 0.f);
        }
        Au[2] = a2;
    }

    // ---- P1: site staging ----
    for (int q = tid; q < SR * SC; q += 256) {
        const int y  = q / SC;
        const int xx = q - y * SC;
        const int gy = r0 + y - 1, gx = xx - 1;
        const bool inb = ((unsigned)gy < 64u) & ((unsigned)gx < 64u);
        const float v = inb ? xin[gy * 64 + gx] : 0.f;

        const float s = __fdividef(v, 1.f + __expf(-v));

        float u  = (v + 2.2f) * 2.5f;
        float mf = floorf(u);
        float t  = u - mf;
        int   m  = (int)mf;
        const bool inr = (m >= 0) && (m <= 10);
        float t2 = t * t, t3 = t2 * t, omt = 1.f - t;
        const float c6 = 1.f / 6.f;
        float wr0 = c6 * omt * omt * omt;
        float wr1 = c6 * (3.f * t3 - 6.f * t2 + 4.f);
        float wr2 = c6 * (-3.f * t3 + 3.f * t2 + 3.f * t + 1.f);
        float wr3 = c6 * t3;
        if (!inr) { wr0 = 0.f; wr1 = 0.f; wr2 = 0.f; wr3 = 0.f; }

        const int base = m - 3;
        float den[8];
        #pragma unroll
        for (int g = 0; g < 8; ++g) {
            const int r = g - base;
            float val = 0.f;
            val = (r == 0) ? wr0 : val;
            val = (r == 1) ? wr1 : val;
            val = (r == 2) ? wr2 : val;
            val = (r == 3) ? wr3 : val;
            den[g] = val;
        }
        u32x4 rec;
        rec[0] = pkf16(den[0], den[1]); rec[1] = pkf16(den[2], den[3]);
        rec[2] = pkf16(den[4], den[5]); rec[3] = pkf16(den[6], den[7]);
        *(u32x4*)&BSb[(y * SCP + xx) * 4] = rec;
        Sil[y * SCP + xx] = s;
    }
    __syncthreads();

    // ---- P2: im2col silu vectors per output pixel ----
    for (int q = tid; q < STRIP * 64; q += 256) {
        const int r = q >> 6, c = q & 63;
        float s9[9];
        #pragma unroll
        for (int dr = 0; dr < 3; ++dr)
            #pragma unroll
            for (int dc = 0; dc < 3; ++dc)
                s9[dr * 3 + dc] = Sil[(r + dr) * SCP + (c + dc)];
        u32x4 ic;
        ic[0] = pkf16(s9[0], s9[1]); ic[1] = pkf16(s9[2], s9[3]);
        ic[2] = pkf16(s9[4], s9[5]); ic[3] = pkf16(s9[6], s9[7]);
        *(u32x4*)&IC0[q * 4] = ic;
        IC1[q] = pkf16(s9[8], 0.f);
    }
    __syncthreads();

    // ---- P3: MFMA over 16 tiles per wave (colb = wv, orow = 0..15) ----
    float* __restrict__ obase = out + (size_t)pl * (8 * 4096);
    const int px = wv * 16 + p;
    const int t0i = cc / 3,       t0j = cc % 3;         // taps 0..3
    const int t1i = (4 + cc) / 3, t1j = (4 + cc) % 3;   // taps 4..7

    for (int orow = 0; orow < STRIP; ++orow) {
        const u32x4 b0 = *(const u32x4*)&BSb[((orow + t0i) * SCP + px + t0j) * 4];
        const u32x4 b1 = *(const u32x4*)&BSb[((orow + t1i) * SCP + px + t1j) * 4];

        const unsigned* a2p;
        if (cc == 0)      a2p = &BSb[((orow + 2) * SCP + px + 2) * 4];
        else if (cc == 1) a2p = &IC0[(orow * 64 + px) * 4];
        else              a2p = ZR;
        u32x4 b2 = *(const u32x4*)a2p;
        const unsigned icv = IC1[orow * 64 + px];
        if (cc == 2) { b2[0] = icv; b2[1] = 0u; b2[2] = 0u; b2[3] = 0u; }

        f32x4 acc = {0.f, 0.f, 0.f, 0.f};
        acc = __builtin_amdgcn_mfma_f32_16x16x32_f16(
            __builtin_bit_cast(h8, Au[0]), __builtin_bit_cast(h8, b0), acc, 0, 0, 0);
        acc = __builtin_amdgcn_mfma_f32_16x16x32_f16(
            __builtin_bit_cast(h8, Au[1]), __builtin_bit_cast(h8, b1), acc, 0, 0, 0);
        acc = __builtin_amdgcn_mfma_f32_16x16x32_f16(
            __builtin_bit_cast(h8, Au[2]), __builtin_bit_cast(h8, b2), acc, 0, 0, 0);

        if (cc < 2) {
            float* o = obase + (size_t)(r0 + orow) * 64 + px;
            #pragma unroll
            for (int r = 0; r < 4; ++r)
                o[(cc * 4 + r) * 4096] = acc[r];
        }
    }
}

extern "C" void kernel_launch(void* const* d_in, const int* in_sizes, int n_in,
                              void* d_out, int out_size, void* d_ws, size_t ws_size,
                              hipStream_t stream) {
    const float* x  = (const float*)d_in[0];
    const float* bw = (const float*)d_in[1];
    const float* sw = (const float*)d_in[2];
    const float* ss = (const float*)d_in[3];
    float* out = (float*)d_out;

    dim3 block(256, 1, 1);
    dim3 grid(1024, 1, 1);   // 256 planes x 4 strips of 16 rows
    hipLaunchKernelGGL(kan_conv_kernel, grid, block, 0, stream, x, bw, sw, ss, out);
}

// Round 12
// 19.483 us; speedup vs baseline: 2.6968x; 1.1036x over previous
//
#include <hip/hip_runtime.h>

typedef float    f32x4 __attribute__((ext_vector_type(4)));
typedef _Float16 h8    __attribute__((ext_vector_type(8)));
typedef unsigned u32x4 __attribute__((ext_vector_type(4)));

#define STRIP 16
#define SR 18          // site rows (strip + halo)
#define SC 66          // site cols (= stride)

__device__ __forceinline__ unsigned pkf16(float a, float b) {
    return __builtin_bit_cast(unsigned, __builtin_amdgcn_cvt_pkrtz(a, b));
}

// Block = 16-row strip of one (b,c) plane; 4 waves; LDS 36.6 KB -> 4 blocks/CU
// resident (grid 1024 = 4 x 256 CUs exactly: single round, no tail).
// P1: stage per-site basis recs (8 f16) in BSb + silu f32 in Sil (UN region).
// P2a: read 9 silu/pixel into regs; P2b (after barrier): write im2col vecs
//      IC0 (taps0-7 f16) + IC1 (tap8 ushort) OVER the Sil region.
// P3: MFMA 16x16x32_f16, K=96: chunks 0-8 spline taps, 9 = base taps0-7,
//     10 = base tap8, 11 = zero. C row = conv n, col = pixel [HW-verified R9].
__global__ __launch_bounds__(256, 4) void kan_conv_kernel(
    const float* __restrict__ x,     // (256, 64, 64)
    const float* __restrict__ bw,    // (8, 9)
    const float* __restrict__ sw,    // (8, 9, 8)
    const float* __restrict__ ss,    // (8, 9)
    float* __restrict__ out)         // (256, 8, 64, 64)
{
    __shared__ __align__(16) unsigned BSb[SR * SC * 4];   // 19,008 B
    __shared__ __align__(16) unsigned UN[4608];           // 18,432 B (Sil | IC0+IC1)

    float*          Sil = (float*)UN;                 // 18*66*4 = 4,752 B (P1..P2a)
    unsigned*       IC0 = UN;                         // 16,384 B (P2b..P3)
    unsigned short* IC1 = (unsigned short*)(UN + 4096); // 2,048 B

    const int tid  = threadIdx.x;
    const int lane = tid & 63;
    const int wv   = tid >> 6;
    const int p    = lane & 15;
    const int cc   = lane >> 4;
    const int pl   = blockIdx.x >> 2;
    const int r0   = (blockIdx.x & 3) * STRIP;

    const float* __restrict__ xin = x + (size_t)pl * 4096;

    // ---- per-lane A-fragments (once) ----
    const int nc = (p < 8) ? p : (p - 8);
    u32x4 Au[3];
    {
        auto packw = [&](int tap) -> u32x4 {
            const float scs = ss[nc * 9 + tap];
            float w[8];
            #pragma unroll
            for (int g = 0; g < 8; ++g) w[g] = sw[(nc * 9 + tap) * 8 + g] * scs;
            u32x4 r;
            r[0] = pkf16(w[0], w[1]); r[1] = pkf16(w[2], w[3]);
            r[2] = pkf16(w[4], w[5]); r[3] = pkf16(w[6], w[7]);
            return r;
        };
        Au[0] = packw(cc);
        Au[1] = packw(4 + cc);
        u32x4 a2 = {0u, 0u, 0u, 0u};
        if (cc == 0) a2 = packw(8);
        else if (cc == 1) {
            a2[0] = pkf16(bw[nc * 9 + 0], bw[nc * 9 + 1]);
            a2[1] = pkf16(bw[nc * 9 + 2], bw[nc * 9 + 3]);
            a2[2] = pkf16(bw[nc * 9 + 4], bw[nc * 9 + 5]);
            a2[3] = pkf16(bw[nc * 9 + 6], bw[nc * 9 + 7]);
        } else if (cc == 2) {
            a2[0] = pkf16(bw[nc * 9 + 8], 0.f);
        }
        Au[2] = a2;
    }

    // ---- P1: site staging ----
    for (int q = tid; q < SR * SC; q += 256) {
        const int y  = q / SC;
        const int xx = q - y * SC;
        const int gy = r0 + y - 1, gx = xx - 1;
        const bool inb = ((unsigned)gy < 64u) & ((unsigned)gx < 64u);
        const float v = inb ? xin[gy * 64 + gx] : 0.f;

        const float s = __fdividef(v, 1.f + __expf(-v));

        float u  = (v + 2.2f) * 2.5f;
        float mf = floorf(u);
        float t  = u - mf;
        int   m  = (int)mf;
        const bool inr = (m >= 0) && (m <= 10);
        float t2 = t * t, t3 = t2 * t, omt = 1.f - t;
        const float c6 = 1.f / 6.f;
        float wr0 = c6 * omt * omt * omt;
        float wr1 = c6 * (3.f * t3 - 6.f * t2 + 4.f);
        float wr2 = c6 * (-3.f * t3 + 3.f * t2 + 3.f * t + 1.f);
        float wr3 = c6 * t3;
        if (!inr) { wr0 = 0.f; wr1 = 0.f; wr2 = 0.f; wr3 = 0.f; }

        const int base = m - 3;
        float den[8];
        #pragma unroll
        for (int g = 0; g < 8; ++g) {
            const int r = g - base;
            float val = 0.f;
            val = (r == 0) ? wr0 : val;
            val = (r == 1) ? wr1 : val;
            val = (r == 2) ? wr2 : val;
            val = (r == 3) ? wr3 : val;
            den[g] = val;
        }
        u32x4 rec;
        rec[0] = pkf16(den[0], den[1]); rec[1] = pkf16(den[2], den[3]);
        rec[2] = pkf16(den[4], den[5]); rec[3] = pkf16(den[6], den[7]);
        *(u32x4*)&BSb[(y * SC + xx) * 4] = rec;
        Sil[y * SC + xx] = s;
    }
    __syncthreads();

    // ---- P2a: im2col silu into registers (static 4 iters; 1024 = 4*256) ----
    u32x4    icr[4];
    unsigned ic1r[4];
    #pragma unroll
    for (int it = 0; it < 4; ++it) {
        const int q = tid + it * 256;
        const int r = q >> 6, c = q & 63;
        float s9[9];
        #pragma unroll
        for (int dr = 0; dr < 3; ++dr)
            #pragma unroll
            for (int dc = 0; dc < 3; ++dc)
                s9[dr * 3 + dc] = Sil[(r + dr) * SC + (c + dc)];
        u32x4 ic;
        ic[0] = pkf16(s9[0], s9[1]); ic[1] = pkf16(s9[2], s9[3]);
        ic[2] = pkf16(s9[4], s9[5]); ic[3] = pkf16(s9[6], s9[7]);
        icr[it]  = ic;
        ic1r[it] = pkf16(s9[8], 0.f);
    }
    __syncthreads();

    // ---- P2b: write IC0/IC1 over the (dead) Sil region ----
    #pragma unroll
    for (int it = 0; it < 4; ++it) {
        const int q = tid + it * 256;
        *(u32x4*)&IC0[q * 4] = icr[it];
        IC1[q] = (unsigned short)(ic1r[it] & 0xFFFFu);
    }
    __syncthreads();

    // ---- P3: MFMA over 16 tiles per wave (colb = wv, orow = 0..15) ----
    float* __restrict__ obase = out + (size_t)pl * (8 * 4096);
    const int px = wv * 16 + p;
    const int t0i = cc / 3,       t0j = cc % 3;         // taps 0..3
    const int t1i = (4 + cc) / 3, t1j = (4 + cc) % 3;   // taps 4..7

    for (int orow = 0; orow < STRIP; ++orow) {
        const u32x4 b0 = *(const u32x4*)&BSb[((orow + t0i) * SC + px + t0j) * 4];
        const u32x4 b1 = *(const u32x4*)&BSb[((orow + t1i) * SC + px + t1j) * 4];

        const unsigned* a2p = (cc == 0) ? &BSb[((orow + 2) * SC + px + 2) * 4]
                                        : &IC0[(orow * 64 + px) * 4];
        u32x4 b2 = *(const u32x4*)a2p;
        const unsigned icv = (unsigned)IC1[orow * 64 + px];
        if (cc == 2) { b2[0] = icv; b2[1] = 0u; b2[2] = 0u; b2[3] = 0u; }
        else if (cc == 3) { b2[0] = 0u; b2[1] = 0u; b2[2] = 0u; b2[3] = 0u; }

        f32x4 acc = {0.f, 0.f, 0.f, 0.f};
        acc = __builtin_amdgcn_mfma_f32_16x16x32_f16(
            __builtin_bit_cast(h8, Au[0]), __builtin_bit_cast(h8, b0), acc, 0, 0, 0);
        acc = __builtin_amdgcn_mfma_f32_16x16x32_f16(
            __builtin_bit_cast(h8, Au[1]), __builtin_bit_cast(h8, b1), acc, 0, 0, 0);
        acc = __builtin_amdgcn_mfma_f32_16x16x32_f16(
            __builtin_bit_cast(h8, Au[2]), __builtin_bit_cast(h8, b2), acc, 0, 0, 0);

        if (cc < 2) {
            float* o = obase + (size_t)(r0 + orow) * 64 + px;
            #pragma unroll
            for (int r = 0; r < 4; ++r)
                o[(cc * 4 + r) * 4096] = acc[r];
        }
    }
}

extern "C" void kernel_launch(void* const* d_in, const int* in_sizes, int n_in,
                              void* d_out, int out_size, void* d_ws, size_t ws_size,
                              hipStream_t stream) {
    const float* x  = (const float*)d_in[0];
    const float* bw = (const float*)d_in[1];
    const float* sw = (const float*)d_in[2];
    const float* ss = (const float*)d_in[3];
    float* out = (float*)d_out;

    dim3 block(256, 1, 1);
    dim3 grid(1024, 1, 1);   // 256 planes x 4 strips of 16 rows
    hipLaunchKernelGGL(kan_conv_kernel, grid, block, 0, stream, x, bw, sw, ss, out);
}